// Round 2
// baseline (596.333 us; speedup 1.0000x reference)
//
#include <hip/hip_runtime.h>

#define NEG_INF -1e30f

constexpr int BLANKC = 6624;
constexpr int NCLS   = 6625;
constexpr int TT     = 512;
constexpr int LL     = 32;
constexpr int NSLOT  = LL + 1;   // 33: slot 0 = blank, slot 1+j = label j
constexpr int BB     = 32;
constexpr int KPT    = TT / 64;  // 8 timesteps per lane

__device__ __forceinline__ float wave_allmax(float v) {
#pragma unroll
    for (int off = 32; off > 0; off >>= 1)
        v = fmaxf(v, __shfl_xor(v, off, 64));
    return v;
}
__device__ __forceinline__ float wave_allsum(float v) {
#pragma unroll
    for (int off = 32; off > 0; off >>= 1)
        v += __shfl_xor(v, off, 64);
    return v;
}

// Fused kernel: one block per batch.
// Phase 1 (4 waves): gather the 33 needed class columns, log-softmax over the
//   TIME axis, write normalized columns into LDS (XOR-swizzled for banks).
// Phase 2 (wave 0): 512-step alpha recursion entirely out of LDS.
// LDS total: 33*512*4 = 67,584 B (gfx950 has 160 KiB/CU).
__global__ __launch_bounds__(256) void ctc_fused(
    const float* __restrict__ x,        // [B, T, C]
    const int*   __restrict__ targets,  // [B, L]
    const int*   __restrict__ input_lengths,
    const int*   __restrict__ target_lengths,
    float*       __restrict__ part)     // [B] per-batch loss
{
    __shared__ float cl[NSLOT * TT];    // cl[slot*TT + ((t+slot)&511)] = lp[b,t,ext_class(slot)]

    const int b    = blockIdx.x;
    const int wv   = threadIdx.x >> 6;
    const int lane = threadIdx.x & 63;

    // ---- Phase 1: stage normalized columns to LDS ----
    for (int slot = wv; slot < NSLOT; slot += 4) {
        const int c = (slot == 0) ? BLANKC : targets[b * LL + slot - 1];
        const float* xb = x + (size_t)b * TT * NCLS + c;
        float v[KPT];
        float m = NEG_INF;
#pragma unroll
        for (int k = 0; k < KPT; ++k) {
            v[k] = xb[(size_t)(lane + 64 * k) * NCLS];
            m = fmaxf(m, v[k]);
        }
        m = wave_allmax(m);
        float ssum = 0.f;
#pragma unroll
        for (int k = 0; k < KPT; ++k) ssum += __expf(v[k] - m);
        ssum = wave_allsum(ssum);
        const float lse = m + __logf(ssum);
#pragma unroll
        for (int k = 0; k < KPT; ++k) {
            const int t = lane + 64 * k;
            cl[slot * TT + ((t + slot) & (TT - 1))] = v[k] - lse;
        }
    }
    __syncthreads();
    if (wv != 0) return;

    // ---- Phase 2: alpha recursion on wave 0 (lane = state s, 0..63; state 64
    // tracked as a redundant scalar: it is a sink with allow_skip=false) ----
    const int s   = lane;
    const int j   = s >> 1;
    const bool odd = (s & 1) != 0;

    const int ext_s = odd ? targets[b * LL + j] : BLANKC;
    bool allow;
    if (!odd)        allow = false;
    else if (s == 1) allow = (ext_s != BLANKC);
    else             allow = (ext_s != BLANKC) && (ext_s != targets[b * LL + j - 1]);

    const int slotS = odd ? (1 + j) : 0;
    const int eoff  = slotS * TT;

    const int ilen = input_lengths[b];
    const int tlen = target_lengths[b];

    float alpha = (s < 2) ? cl[eoff + ((0 + slotS) & (TT - 1))] : NEG_INF;
    float a64   = NEG_INF;

#pragma unroll 4
    for (int t = 1; t < TT; ++t) {
        const float e  = cl[eoff + ((t + slotS) & (TT - 1))]; // recurrence-independent -> pipelines
        const float eb = cl[t];                               // blank col, broadcast read (free)

        float am1 = __shfl_up(alpha, 1, 64);
        float am2 = __shfl_up(alpha, 2, 64);
        const float a63 = __shfl(alpha, 63, 64);
        if (s == 0) am1 = NEG_INF;
        if (s < 2 || !allow) am2 = NEG_INF;

        const float m  = fmaxf(fmaxf(alpha, am1), am2);
        const float na = m + __logf(__expf(alpha - m) + __expf(am1 - m) + __expf(am2 - m)) + e;
        const float m2   = fmaxf(a64, a63);
        const float na64 = m2 + __logf(__expf(a64 - m2) + __expf(a63 - m2)) + eb;

        const bool live = (t < ilen);
        alpha = live ? na   : alpha;
        a64   = live ? na64 : a64;
    }

    const int idx1 = 2 * tlen;
    const int idx2 = max(2 * tlen - 1, 0);
    const float l1 = (idx1 >= 64) ? a64 : __shfl(alpha, idx1, 64);
    const float l2 = (idx2 >= 64) ? a64 : __shfl(alpha, idx2, 64);
    const float mm = fmaxf(l1, l2);
    float loss = -(mm + __logf(__expf(l1 - mm) + __expf(l2 - mm)));
    if (loss > 1e20f) loss = 0.f;
    loss /= (float)max(tlen, 1);
    if (s == 0) part[b] = loss;
}

// Final mean over batch into d_out (d_out is re-poisoned each call -> must write).
__global__ __launch_bounds__(64) void ctc_reduce(
    const float* __restrict__ part, float* __restrict__ out)
{
    const int lane = threadIdx.x;
    float v = (lane < BB) ? part[lane] : 0.f;
#pragma unroll
    for (int off = 32; off > 0; off >>= 1) v += __shfl_xor(v, off, 64);
    if (lane == 0) out[0] = v / (float)BB;
}

extern "C" void kernel_launch(void* const* d_in, const int* in_sizes, int n_in,
                              void* d_out, int out_size, void* d_ws, size_t ws_size,
                              hipStream_t stream) {
    const float* lp      = (const float*)d_in[0];   // [B, T, C] fp32
    const int*   targets = (const int*)d_in[1];     // [B, L]
    const int*   ilen    = (const int*)d_in[2];     // [B]
    const int*   tlen    = (const int*)d_in[3];     // [B]
    float* out  = (float*)d_out;
    float* part = (float*)d_ws;                     // [B]

    ctc_fused<<<BB, 256, 0, stream>>>(lp, targets, ilen, tlen, part);
    ctc_reduce<<<1, 64, 0, stream>>>(part, out);
}

// Round 3
// 579.204 us; speedup vs baseline: 1.0296x; 1.0296x over previous
//
#include <hip/hip_runtime.h>

#define NEG_INF -1e30f

constexpr int BLANKC = 6624;
constexpr int NCLS   = 6625;
constexpr int TT     = 512;
constexpr int LL     = 32;
constexpr int NSLOT  = LL + 1;   // 33: slot 0 = blank, slot 1+j = label j
constexpr int BB     = 32;
constexpr int KPT    = TT / 64;  // 8 timesteps per lane

__device__ __forceinline__ float wave_allmax(float v) {
#pragma unroll
    for (int off = 32; off > 0; off >>= 1)
        v = fmaxf(v, __shfl_xor(v, off, 64));
    return v;
}
__device__ __forceinline__ float wave_allsum(float v) {
#pragma unroll
    for (int off = 32; off > 0; off >>= 1)
        v += __shfl_xor(v, off, 64);
    return v;
}

// shfl_up by 1 across the full 64-lane wave via DPP wave_shr:1 (ctrl 0x138).
// bound_ctrl=false keeps `old` in lane 0 -> boundary gets NEG_INF for free.
// ~2 cy on the VALU vs ~30-40 cy for ds_permute (what __shfl_up lowers to).
__device__ __forceinline__ float shfl_up1_neginf(float x) {
    int r = __builtin_amdgcn_update_dpp(
        __float_as_int(NEG_INF), __float_as_int(x),
        0x138 /* wave_shr:1 */, 0xF, 0xF, false);
    return __int_as_float(r);
}

// Fused kernel: one block per batch.
// Phase 1 (4 waves): gather the 33 needed class columns, log-softmax over the
//   TIME axis, write normalized columns into LDS (XOR-swizzled for banks).
// Phase 2 (wave 0): alpha recursion entirely out of LDS, DPP lane shifts.
// LDS: 33*512*4 = 67,584 B.
__global__ __launch_bounds__(256) void ctc_fused(
    const float* __restrict__ x,        // [B, T, C]
    const int*   __restrict__ targets,  // [B, L]
    const int*   __restrict__ input_lengths,
    const int*   __restrict__ target_lengths,
    float*       __restrict__ part)     // [B] per-batch loss
{
    __shared__ float cl[NSLOT * TT];    // cl[slot*TT + ((t+slot)&511)] = lp[b,t,ext_class(slot)]

    const int b    = blockIdx.x;
    const int wv   = threadIdx.x >> 6;
    const int lane = threadIdx.x & 63;

    // ---- Phase 1: stage normalized columns to LDS ----
    for (int slot = wv; slot < NSLOT; slot += 4) {
        const int c = (slot == 0) ? BLANKC : targets[b * LL + slot - 1];
        const float* xb = x + (size_t)b * TT * NCLS + c;
        float v[KPT];
        float m = NEG_INF;
#pragma unroll
        for (int k = 0; k < KPT; ++k) {
            v[k] = xb[(size_t)(lane + 64 * k) * NCLS];
            m = fmaxf(m, v[k]);
        }
        m = wave_allmax(m);
        float ssum = 0.f;
#pragma unroll
        for (int k = 0; k < KPT; ++k) ssum += __expf(v[k] - m);
        ssum = wave_allsum(ssum);
        const float lse = m + __logf(ssum);
#pragma unroll
        for (int k = 0; k < KPT; ++k) {
            const int t = lane + 64 * k;
            cl[slot * TT + ((t + slot) & (TT - 1))] = v[k] - lse;
        }
    }
    __syncthreads();
    if (wv != 0) return;

    // ---- Phase 2: alpha recursion on wave 0 (lane = state s, 0..63; state 64
    // tracked as a redundant scalar: it is a sink with allow_skip=false) ----
    const int s   = lane;
    const int j   = s >> 1;
    const bool odd = (s & 1) != 0;

    const int ext_s = odd ? targets[b * LL + j] : BLANKC;
    bool allow;
    if (!odd)        allow = false;
    else if (s == 1) allow = (ext_s != BLANKC);
    else             allow = (ext_s != BLANKC) && (ext_s != targets[b * LL + j - 1]);

    const int slotS = odd ? (1 + j) : 0;
    const int eoff  = slotS * TT;

    const int ilen = input_lengths[b];
    const int tlen = target_lengths[b];

    float alpha = (s < 2) ? cl[eoff + ((0 + slotS) & (TT - 1))] : NEG_INF;
    float a64   = NEG_INF;

    // Freeze-past-input_length == simply stop updating: loop to min(ilen,TT).
    const int tstop = (ilen < TT) ? ilen : TT;
#pragma unroll 8
    for (int t = 1; t < tstop; ++t) {
        const float e  = cl[eoff + ((t + slotS) & (TT - 1))]; // recurrence-independent -> pipelines
        const float eb = cl[t];                               // blank col (broadcast read)

        const float am1 = shfl_up1_neginf(alpha);             // lane0 -> NEG_INF via bound_ctrl
        float am2       = shfl_up1_neginf(am1);               // lanes 0,1 -> NEG_INF
        const float a63 = __shfl(alpha, 63, 64);
        if (!allow) am2 = NEG_INF;

        const float m  = fmaxf(fmaxf(alpha, am1), am2);       // v_max3_f32
        const float na = m + __logf(__expf(alpha - m) + __expf(am1 - m) + __expf(am2 - m)) + e;
        const float m2   = fmaxf(a64, a63);
        const float na64 = m2 + __logf(__expf(a64 - m2) + __expf(a63 - m2)) + eb;

        alpha = na;
        a64   = na64;
    }

    const int idx1 = 2 * tlen;
    const int idx2 = max(2 * tlen - 1, 0);
    const float l1 = (idx1 >= 64) ? a64 : __shfl(alpha, idx1, 64);
    const float l2 = (idx2 >= 64) ? a64 : __shfl(alpha, idx2, 64);
    const float mm = fmaxf(l1, l2);
    float loss = -(mm + __logf(__expf(l1 - mm) + __expf(l2 - mm)));
    if (loss > 1e20f) loss = 0.f;
    loss /= (float)max(tlen, 1);
    if (s == 0) part[b] = loss;
}

// Final mean over batch into d_out (d_out is re-poisoned each call -> must write).
__global__ __launch_bounds__(64) void ctc_reduce(
    const float* __restrict__ part, float* __restrict__ out)
{
    const int lane = threadIdx.x;
    float v = (lane < BB) ? part[lane] : 0.f;
#pragma unroll
    for (int off = 32; off > 0; off >>= 1) v += __shfl_xor(v, off, 64);
    if (lane == 0) out[0] = v / (float)BB;
}

extern "C" void kernel_launch(void* const* d_in, const int* in_sizes, int n_in,
                              void* d_out, int out_size, void* d_ws, size_t ws_size,
                              hipStream_t stream) {
    const float* lp      = (const float*)d_in[0];   // [B, T, C] fp32
    const int*   targets = (const int*)d_in[1];     // [B, L]
    const int*   ilen    = (const int*)d_in[2];     // [B]
    const int*   tlen    = (const int*)d_in[3];     // [B]
    float* out  = (float*)d_out;
    float* part = (float*)d_ws;                     // [B]

    ctc_fused<<<BB, 256, 0, stream>>>(lp, targets, ilen, tlen, part);
    ctc_reduce<<<1, 64, 0, stream>>>(part, out);
}